// Round 12
// baseline (5813.356 us; speedup 1.0000x reference)
//
#include <hip/hip_runtime.h>
#include <math.h>

#define T_STEPS 512
#define BATCH   16
#define DIM     1024
#define M_TOTAL (T_STEPS*BATCH)              // 8192
#define OUT_SEC ((size_t)M_TOTAL*DIM)        // 8388608 floats (output section)
#define BD      (BATCH*DIM)
#define CNT_STRIDE 32

// fused ws layout (32-bit words):
//   tagbuf: 2*BD uint2 packets  @ word 0        (256 KB)
//   cnt_pre[128]                @ word 65536    (GEMM tiles, target 8)
//   cnt_gate4[128]              @ word 65664    (gate groups of 4 t, target 8)
#define WSW_TAG    0
#define WSW_CPRE   65536
#define WSW_CGATE  (65536 + 128)
#define FUSED_WORDS (65536 + 256)
#define FUSED_BYTES ((size_t)FUSED_WORDS*4)    // 263168 B
#define TAG_BYTES   ((size_t)2*BD*8)           // 256 KB (r10 fallback)

// fused grid roles
#define NB_RNN  256
#define NB_GATE 1024
#define NB_GEMM 1024
#define NB_ALL  (NB_RNN + NB_GATE + NB_GEMM)

// ---------------------------------------------------------------------------
__device__ __forceinline__ float wred64(float v){
  #pragma unroll
  for (int off = 32; off >= 1; off >>= 1) v += __shfl_xor(v, off, 64);
  return v;
}

__device__ __forceinline__ unsigned llc_load_u32(const unsigned* p){
  unsigned v;
  asm volatile("global_load_dword %0, %1, off sc0 sc1\n\ts_waitcnt vmcnt(0)"
               : "=&v"(v) : "v"(p) : "memory");
  return v;
}

__device__ __forceinline__ void llc_load2_f32(const float* p1, const float* p2,
                                              float& v1, float& v2){
  asm volatile("global_load_dword %0, %2, off sc0 sc1\n\t"
               "global_load_dword %1, %3, off sc0 sc1\n\t"
               "s_waitcnt vmcnt(0)"
               : "=&v"(v1), "=&v"(v2) : "v"(p1), "v"(p2) : "memory");
}

// LLC-bypass 16B store as two 8B relaxed agent atomics (verified construct —
// same as the tag packets; avoids float4 asm-input, which clang rejects).
__device__ __forceinline__ void llc_store_f4(float* p, float4 v){
  const unsigned long long lo =
      ((unsigned long long)__float_as_uint(v.y) << 32) |
      (unsigned long long)__float_as_uint(v.x);
  const unsigned long long hi =
      ((unsigned long long)__float_as_uint(v.w) << 32) |
      (unsigned long long)__float_as_uint(v.z);
  unsigned long long* q = reinterpret_cast<unsigned long long*>(p);
  __hip_atomic_store(q,     lo, __ATOMIC_RELAXED, __HIP_MEMORY_SCOPE_AGENT);
  __hip_atomic_store(q + 1, hi, __ATOMIC_RELAXED, __HIP_MEMORY_SCOPE_AGENT);
}

#define KA(v) asm volatile("" : "+v"(v.x), "+v"(v.y), "+v"(v.z), "+v"(v.w))

// ---------------------------------------------------------------------------
// FUSED kernel. Roles by blockIdx:
//   [0,256)      RNN: persistent recurrence (r10 structure), per-step
//                pre/gate gated by cnt_pre/cnt_gate4 (checked 1x per 4 steps,
//                prefetched in the shadow of the next h-poll).
//   [256,1280)   gate: entmax-1.5, 8 rows/block, LLC stores + counter.
//   [1280,2304)  GEMM: pre = X@Wx^T+b, 64x128 tile, bm-major (early t first),
//                LLC stores + counter.
// launch_bounds(512,4) caps VGPR at 128 -> >=2 blocks/CU -> the 256 resident
// RNN blocks can never starve prep blocks (deadlock-free under any dispatch).
__global__ __launch_bounds__(512, 4) void fused_kernel(
    const float* __restrict__ X, const float* __restrict__ z,
    const float* __restrict__ h0, const float* __restrict__ Wx,
    const float* __restrict__ Wh, const float* __restrict__ bias,
    float* __restrict__ out, unsigned* __restrict__ ws)
{
  __shared__ float smem[3264];              // gemm: 64*17 + 128*17; rnn: 2048
  const int tid = threadIdx.x;
  const int bid = blockIdx.x;
  float* out_h = out + OUT_SEC;

  if (bid < NB_RNN){
    // ---------------- RNN role ----------------
    const int lane = tid & 63;
    const int w    = tid >> 6;
    const int b    = bid >> 4;
    const int s    = bid & 15;
    const int dbase = s*64 + w*8;
    float* hbuf = smem;                     // [2][1024]

    uint2*    tagbuf = reinterpret_cast<uint2*>(ws + WSW_TAG);
    unsigned* cpre   = ws + WSW_CPRE;
    unsigned* cgate  = ws + WSW_CGATE;

    float4 wreg[8][4];
    #pragma unroll
    for (int r = 0; r < 8; ++r)
      #pragma unroll
      for (int j = 0; j < 4; ++j)
        wreg[r][j] = *reinterpret_cast<const float4*>(
            Wh + (size_t)(dbase + r)*DIM + lane*4 + j*256);
    KA(wreg[0][0]); KA(wreg[0][1]); KA(wreg[0][2]); KA(wreg[0][3]);
    KA(wreg[1][0]); KA(wreg[1][1]); KA(wreg[1][2]); KA(wreg[1][3]);
    KA(wreg[2][0]); KA(wreg[2][1]); KA(wreg[2][2]); KA(wreg[2][3]);
    KA(wreg[3][0]); KA(wreg[3][1]); KA(wreg[3][2]); KA(wreg[3][3]);
    KA(wreg[4][0]); KA(wreg[4][1]); KA(wreg[4][2]); KA(wreg[4][3]);
    KA(wreg[5][0]); KA(wreg[5][1]); KA(wreg[5][2]); KA(wreg[5][3]);
    KA(wreg[6][0]); KA(wreg[6][1]); KA(wreg[6][2]); KA(wreg[6][3]);
    KA(wreg[7][0]); KA(wreg[7][1]); KA(wreg[7][2]); KA(wreg[7][3]);

    // h[0] = h0 in the validated h section
    if (tid < 16)
      reinterpret_cast<float4*>(out_h + (size_t)b*DIM + s*64)[tid] =
          reinterpret_cast<const float4*>(h0 + (size_t)b*DIM + s*64)[tid];

    const int  myrow  = lane >> 3;
    const bool active = ((lane & 7) == 0);
    const size_t dmy  = (size_t)dbase + myrow;

    float pre_v = 0.f, gate_v = 0.f;
    if (active){
      while (llc_load_u32(cpre  + 0) < 8u) {}
      while (llc_load_u32(cgate + 0) < 8u) {}
      llc_load2_f32(out_h + (size_t)1*BD + (size_t)b*DIM + dmy,
                    out   +                (size_t)b*DIM + dmy, pre_v, gate_v);
    }

    for (int t = 0; t < T_STEPS; ++t){
      // ---- acquire h[t][b] into LDS (distributed poll) ----
      if (t == 0){
        const float2 hl = *reinterpret_cast<const float2*>(h0 + (size_t)b*DIM + 2*tid);
        *reinterpret_cast<float2*>(&hbuf[2*tid]) = hl;
      } else {
        const uint2* pp = tagbuf + (size_t)(t & 1)*BD + (size_t)b*DIM + 2*tid;
        const unsigned want = (unsigned)t;
        float4 q;
        do {
          asm volatile("global_load_dwordx4 %0, %1, off sc0 sc1\n\t"
                       "s_waitcnt vmcnt(0)"
                       : "=&v"(q) : "v"(pp) : "memory");
        } while (__float_as_uint(q.y) != want || __float_as_uint(q.w) != want);
        *reinterpret_cast<float2*>(&hbuf[(t & 1)*DIM + 2*tid]) = make_float2(q.x, q.z);
      }
      __syncthreads();

      const float* src = &hbuf[(t & 1)*DIM];
      const float4 hv0 = *reinterpret_cast<const float4*>(src + lane*4);
      const float4 hv1 = *reinterpret_cast<const float4*>(src + 256 + lane*4);
      const float4 hv2 = *reinterpret_cast<const float4*>(src + 512 + lane*4);
      const float4 hv3 = *reinterpret_cast<const float4*>(src + 768 + lane*4);

      float v0,v1,v2,v3,v4,v5,v6,v7;
      #define DOTROW(R, OUTV)                                            \
        { const float4 w0=wreg[R][0], w1=wreg[R][1],                     \
                       w2=wreg[R][2], w3=wreg[R][3];                     \
          float a_ = 0.f;                                                \
          a_ = fmaf(w0.x,hv0.x,fmaf(w0.y,hv0.y,fmaf(w0.z,hv0.z,fmaf(w0.w,hv0.w,a_)))); \
          a_ = fmaf(w1.x,hv1.x,fmaf(w1.y,hv1.y,fmaf(w1.z,hv1.z,fmaf(w1.w,hv1.w,a_)))); \
          a_ = fmaf(w2.x,hv2.x,fmaf(w2.y,hv2.y,fmaf(w2.z,hv2.z,fmaf(w2.w,hv2.w,a_)))); \
          a_ = fmaf(w3.x,hv3.x,fmaf(w3.y,hv3.y,fmaf(w3.z,hv3.z,fmaf(w3.w,hv3.w,a_)))); \
          OUTV = a_; }
      DOTROW(0,v0) DOTROW(1,v1) DOTROW(2,v2) DOTROW(3,v3)
      DOTROW(4,v4) DOTROW(5,v5) DOTROW(6,v6) DOTROW(7,v7)
      #undef DOTROW

      // 10-shuffle folded reduction; lane 8r holds row r
      const bool sA = (lane & 32) != 0;
      float a0 = (sA? v4 : v0) + __shfl_xor(sA? v0 : v4, 32, 64);
      float a1 = (sA? v5 : v1) + __shfl_xor(sA? v1 : v5, 32, 64);
      float a2 = (sA? v6 : v2) + __shfl_xor(sA? v2 : v6, 32, 64);
      float a3 = (sA? v7 : v3) + __shfl_xor(sA? v3 : v7, 32, 64);
      const bool sB = (lane & 16) != 0;
      float b0 = (sB? a2 : a0) + __shfl_xor(sB? a0 : a2, 16, 64);
      float b1 = (sB? a3 : a1) + __shfl_xor(sB? a1 : a3, 16, 64);
      const bool sC = (lane & 8) != 0;
      float c0 = (sC? b1 : b0) + __shfl_xor(sC? b0 : b1, 8, 64);
      c0 += __shfl_xor(c0, 4, 64);
      c0 += __shfl_xor(c0, 2, 64);
      c0 += __shfl_xor(c0, 1, 64);

      if (active){
        const float vv = pre_v + c0;
        const float e  = __expf(2.0f * vv);
        const float hn = 1.0f - 2.0f / (e + 1.0f);   // tanh
        if (t != T_STEPS - 1){
          const unsigned long long pkt =
              ((unsigned long long)(unsigned)(t + 1) << 32) |
              (unsigned long long)__float_as_uint(hn);
          __hip_atomic_store(
              reinterpret_cast<unsigned long long*>(
                  tagbuf + (size_t)((t + 1) & 1)*BD + (size_t)b*DIM + dmy),
              pkt, __ATOMIC_RELAXED, __HIP_MEMORY_SCOPE_AGENT);
        }
        out_h[(size_t)(t+1)*BD + (size_t)b*DIM + dmy] = hn;          // h (cached)
        out  [(size_t)t*BD     + (size_t)b*DIM + dmy] = hn * gate_v; // out (cached)

        // prefetch pre/gate for t+1 (in the shadow of the next h-poll)
        if (t + 1 < T_STEPS){
          const int g = (t + 1) >> 2;
          if (((t + 1) & 3) == 0){
            while (llc_load_u32(cpre  + g) < 8u) {}
            while (llc_load_u32(cgate + g) < 8u) {}
          }
          llc_load2_f32(out_h + (size_t)(t+2)*BD + (size_t)b*DIM + dmy,
                        out   + (size_t)(t+1)*BD + (size_t)b*DIM + dmy,
                        pre_v, gate_v);
        }
      }
    }
  } else if (bid < NB_RNN + NB_GATE){
    // ---------------- gate role (entmax-1.5, 8 rows/block) ----------------
    const int gb   = bid - NB_RNN;
    const int row  = gb*8 + (tid >> 6);
    const int lane = tid & 63;
    const float* zr = z + (size_t)row * DIM;

    float x[16];
    #pragma unroll
    for (int e = 0; e < 4; ++e){
      float4 v = *reinterpret_cast<const float4*>(zr + e*256 + lane*4);
      x[e*4+0]=v.x; x[e*4+1]=v.y; x[e*4+2]=v.z; x[e*4+3]=v.w;
    }
    float m = x[0];
    #pragma unroll
    for (int i = 1; i < 16; ++i) m = fmaxf(m, x[i]);
    #pragma unroll
    for (int off = 32; off >= 1; off >>= 1) m = fmaxf(m, __shfl_xor(m, off, 64));

    float lo = m - 1.0f, hi = m;
    for (int it = 0; it < 30; ++it){
      float mid = 0.5f*(lo + hi);
      float f = 0.f;
      #pragma unroll
      for (int i = 0; i < 16; ++i) f += fmaxf(x[i] - mid, 0.f);
      f = wred64(f);
      if (f >= 1.0f) lo = mid; else hi = mid;
    }
    float sums = 0.f, kc = 0.f;
    #pragma unroll
    for (int i = 0; i < 16; ++i){ if (x[i] > lo){ sums += x[i]; kc += 1.f; } }
    sums = wred64(sums); kc = wred64(kc);
    const float tau = (sums - 1.0f) / kc;

    float p[16]; float ps = 0.f;
    #pragma unroll
    for (int i = 0; i < 16; ++i){ p[i] = sqrtf(fmaxf(x[i] - tau, 0.f)); ps += p[i]; }
    ps = wred64(ps);
    const float inv = 1.0f / (ps + 1e-10f);

    float* go = out + (size_t)row * DIM;
    #pragma unroll
    for (int e = 0; e < 4; ++e){
      float4 v; v.x=p[e*4]*inv; v.y=p[e*4+1]*inv; v.z=p[e*4+2]*inv; v.w=p[e*4+3]*inv;
      llc_store_f4(go + e*256 + lane*4, v);
    }
    asm volatile("s_waitcnt vmcnt(0)" ::: "memory");
    __syncthreads();
    if (tid == 0)
      __hip_atomic_fetch_add(ws + WSW_CGATE + (gb >> 3), 1u,
                             __ATOMIC_RELAXED, __HIP_MEMORY_SCOPE_AGENT);
  } else {
    // ---------------- GEMM role: pre = X@Wx^T + b, 64x128 tile ----------------
    const int gb = bid - NB_RNN - NB_GATE;
    const int bm = gb >> 3, bn = gb & 7;        // bm-major: early t first
    const int m0 = bm*64, n0 = bn*128;
    float* a_s = smem;                           // [64][17]
    float* w_s = smem + 64*17;                   // [128][17]
    const int arow = tid >> 3, acol = (tid & 7)*2;
    const int wrow = tid >> 2, wcol = (tid & 3)*4;
    const int tx = tid & 31, ty = tid >> 5;

    float acc[4][4] = {};

    for (int k0 = 0; k0 < DIM; k0 += 16){
      const float2 av = *reinterpret_cast<const float2*>(
          X  + (size_t)(m0+arow)*DIM + k0 + acol);
      const float4 wv = *reinterpret_cast<const float4*>(
          Wx + (size_t)(n0+wrow)*DIM + k0 + wcol);
      __syncthreads();
      a_s[arow*17 + acol]   = av.x;
      a_s[arow*17 + acol+1] = av.y;
      w_s[wrow*17 + wcol+0] = wv.x;
      w_s[wrow*17 + wcol+1] = wv.y;
      w_s[wrow*17 + wcol+2] = wv.z;
      w_s[wrow*17 + wcol+3] = wv.w;
      __syncthreads();
      #pragma unroll
      for (int k = 0; k < 16; ++k){
        float af[4], wf[4];
        #pragma unroll
        for (int i = 0; i < 4; ++i) af[i] = a_s[(ty*4+i)*17 + k];
        #pragma unroll
        for (int j = 0; j < 4; ++j) wf[j] = w_s[(tx*4+j)*17 + k];
        #pragma unroll
        for (int i = 0; i < 4; ++i)
          #pragma unroll
          for (int j = 0; j < 4; ++j) acc[i][j] = fmaf(af[i], wf[j], acc[i][j]);
      }
    }

    const float4 bv = *reinterpret_cast<const float4*>(bias + n0 + tx*4);
    #pragma unroll
    for (int i = 0; i < 4; ++i){
      float4 v;
      v.x = acc[i][0]+bv.x; v.y = acc[i][1]+bv.y;
      v.z = acc[i][2]+bv.z; v.w = acc[i][3]+bv.w;
      // pre[t,b] -> h slot t+1  (row m+16)
      llc_store_f4(out_h + (size_t)(m0+ty*4+i+BATCH)*DIM + n0 + tx*4, v);
    }
    asm volatile("s_waitcnt vmcnt(0)" ::: "memory");
    __syncthreads();
    if (tid == 0)
      __hip_atomic_fetch_add(ws + WSW_CPRE + bm, 1u,
                             __ATOMIC_RELAXED, __HIP_MEMORY_SCOPE_AGENT);
  }
}

// ===========================================================================
// Fallback path (r10, verified 1229 us): separate prep + tagged rnn.
// ===========================================================================
__global__ __launch_bounds__(256) void prep_kernel(const float* __restrict__ X,
                                                   const float* __restrict__ Wx,
                                                   const float* __restrict__ bias,
                                                   float* __restrict__ out_h,
                                                   const float* __restrict__ z,
                                                   float* __restrict__ gate_out){
  const int tid = threadIdx.x;
  if (blockIdx.x < 2048){
    __shared__ float a_s[64][17];
    __shared__ float w_s[64][17];
    const int bm = blockIdx.x & 127, bn = blockIdx.x >> 7;
    const int m0 = bm*64, n0 = bn*64;
    const int lr = tid >> 2, lc = (tid & 3) * 4;
    const int tx = tid & 15, ty = tid >> 4;
    float acc[4][4] = {};
    for (int k0 = 0; k0 < DIM; k0 += 16){
      float4 av = *reinterpret_cast<const float4*>(X  + (size_t)(m0+lr)*DIM + k0 + lc);
      float4 wv = *reinterpret_cast<const float4*>(Wx + (size_t)(n0+lr)*DIM + k0 + lc);
      __syncthreads();
      a_s[lr][lc+0]=av.x; a_s[lr][lc+1]=av.y; a_s[lr][lc+2]=av.z; a_s[lr][lc+3]=av.w;
      w_s[lr][lc+0]=wv.x; w_s[lr][lc+1]=wv.y; w_s[lr][lc+2]=wv.z; w_s[lr][lc+3]=wv.w;
      __syncthreads();
      #pragma unroll
      for (int k = 0; k < 16; ++k){
        float af[4], wf[4];
        #pragma unroll
        for (int i = 0; i < 4; ++i) af[i] = a_s[ty*4+i][k];
        #pragma unroll
        for (int j = 0; j < 4; ++j) wf[j] = w_s[tx*4+j][k];
        #pragma unroll
        for (int i = 0; i < 4; ++i)
          #pragma unroll
          for (int j = 0; j < 4; ++j) acc[i][j] = fmaf(af[i], wf[j], acc[i][j]);
      }
    }
    const float4 bv = *reinterpret_cast<const float4*>(bias + n0 + tx*4);
    #pragma unroll
    for (int i = 0; i < 4; ++i){
      float4 v;
      v.x = acc[i][0]+bv.x; v.y = acc[i][1]+bv.y; v.z = acc[i][2]+bv.z; v.w = acc[i][3]+bv.w;
      *reinterpret_cast<float4*>(out_h + (size_t)(m0+ty*4+i+BATCH)*DIM + n0 + tx*4) = v;
    }
  } else {
    const int bid  = blockIdx.x - 2048;
    const int row  = bid * 4 + (tid >> 6);
    const int lane = tid & 63;
    const float* zr = z + (size_t)row * DIM;
    float x[16];
    #pragma unroll
    for (int e = 0; e < 4; ++e){
      float4 v = *reinterpret_cast<const float4*>(zr + e*256 + lane*4);
      x[e*4+0]=v.x; x[e*4+1]=v.y; x[e*4+2]=v.z; x[e*4+3]=v.w;
    }
    float m = x[0];
    #pragma unroll
    for (int i = 1; i < 16; ++i) m = fmaxf(m, x[i]);
    #pragma unroll
    for (int off = 32; off >= 1; off >>= 1) m = fmaxf(m, __shfl_xor(m, off, 64));
    float lo = m - 1.0f, hi = m;
    for (int it = 0; it < 30; ++it){
      float mid = 0.5f*(lo + hi);
      float f = 0.f;
      #pragma unroll
      for (int i = 0; i < 16; ++i) f += fmaxf(x[i] - mid, 0.f);
      f = wred64(f);
      if (f >= 1.0f) lo = mid; else hi = mid;
    }
    float s = 0.f, kc = 0.f;
    #pragma unroll
    for (int i = 0; i < 16; ++i){ if (x[i] > lo){ s += x[i]; kc += 1.f; } }
    s = wred64(s); kc = wred64(kc);
    const float tau = (s - 1.0f) / kc;
    float p[16]; float ps = 0.f;
    #pragma unroll
    for (int i = 0; i < 16; ++i){ p[i] = sqrtf(fmaxf(x[i] - tau, 0.f)); ps += p[i]; }
    ps = wred64(ps);
    const float inv = 1.0f / (ps + 1e-10f);
    float* go = gate_out + (size_t)row * DIM;
    #pragma unroll
    for (int e = 0; e < 4; ++e){
      float4 v; v.x=p[e*4]*inv; v.y=p[e*4+1]*inv; v.z=p[e*4+2]*inv; v.w=p[e*4+3]*inv;
      *reinterpret_cast<float4*>(go + e*256 + lane*4) = v;
    }
  }
}

__global__ __launch_bounds__(512, 1) void rnn_tag(const float* __restrict__ h0,
                                                  const float* __restrict__ Wh,
                                                  float* __restrict__ out,
                                                  uint2* __restrict__ tagbuf){
  float* out_h = out + OUT_SEC;
  const int tid  = threadIdx.x;
  const int lane = tid & 63;
  const int w    = tid >> 6;
  const int b    = blockIdx.x >> 4;
  const int s    = blockIdx.x & 15;
  const int dbase = s*64 + w*8;
  __shared__ float hbuf[2][DIM];

  float4 wreg[8][4];
  #pragma unroll
  for (int r = 0; r < 8; ++r)
    #pragma unroll
    for (int j = 0; j < 4; ++j)
      wreg[r][j] = *reinterpret_cast<const float4*>(
          Wh + (size_t)(dbase + r)*DIM + lane*4 + j*256);
  KA(wreg[0][0]); KA(wreg[0][1]); KA(wreg[0][2]); KA(wreg[0][3]);
  KA(wreg[1][0]); KA(wreg[1][1]); KA(wreg[1][2]); KA(wreg[1][3]);
  KA(wreg[2][0]); KA(wreg[2][1]); KA(wreg[2][2]); KA(wreg[2][3]);
  KA(wreg[3][0]); KA(wreg[3][1]); KA(wreg[3][2]); KA(wreg[3][3]);
  KA(wreg[4][0]); KA(wreg[4][1]); KA(wreg[4][2]); KA(wreg[4][3]);
  KA(wreg[5][0]); KA(wreg[5][1]); KA(wreg[5][2]); KA(wreg[5][3]);
  KA(wreg[6][0]); KA(wreg[6][1]); KA(wreg[6][2]); KA(wreg[6][3]);
  KA(wreg[7][0]); KA(wreg[7][1]); KA(wreg[7][2]); KA(wreg[7][3]);

  if (tid < 16)
    reinterpret_cast<float4*>(out_h + (size_t)b*DIM + s*64)[tid] =
        reinterpret_cast<const float4*>(h0 + (size_t)b*DIM + s*64)[tid];

  const int myrow   = lane >> 3;
  const bool active = ((lane & 7) == 0);

  for (int t = 0; t < T_STEPS; ++t){
    float pre_v = 0.f, gate_v = 0.f;
    if (active){
      const size_t d = dbase + myrow;
      pre_v  = out_h[(size_t)(t+1)*BD + (size_t)b*DIM + d];
      gate_v = out  [(size_t)t*BD     + (size_t)b*DIM + d];
    }
    if (t == 0){
      const float2 hl = *reinterpret_cast<const float2*>(h0 + (size_t)b*DIM + 2*tid);
      *reinterpret_cast<float2*>(&hbuf[0][2*tid]) = hl;
    } else {
      const uint2* pp = tagbuf + (size_t)(t & 1)*BD + (size_t)b*DIM + 2*tid;
      const unsigned want = (unsigned)t;
      float4 q;
      do {
        asm volatile("global_load_dwordx4 %0, %1, off sc0 sc1\n\t"
                     "s_waitcnt vmcnt(0)"
                     : "=&v"(q) : "v"(pp) : "memory");
      } while (__float_as_uint(q.y) != want || __float_as_uint(q.w) != want);
      *reinterpret_cast<float2*>(&hbuf[t & 1][2*tid]) = make_float2(q.x, q.z);
    }
    __syncthreads();
    const float* src = &hbuf[t & 1][0];
    const float4 hv0 = *reinterpret_cast<const float4*>(src + lane*4);
    const float4 hv1 = *reinterpret_cast<const float4*>(src + 256 + lane*4);
    const float4 hv2 = *reinterpret_cast<const float4*>(src + 512 + lane*4);
    const float4 hv3 = *reinterpret_cast<const float4*>(src + 768 + lane*4);

    float v0,v1,v2,v3,v4,v5,v6,v7;
    #define DOTROW(R, OUTV)                                            \
      { const float4 w0=wreg[R][0], w1=wreg[R][1],                     \
                     w2=wreg[R][2], w3=wreg[R][3];                     \
        float a_ = 0.f;                                                \
        a_ = fmaf(w0.x,hv0.x,fmaf(w0.y,hv0.y,fmaf(w0.z,hv0.z,fmaf(w0.w,hv0.w,a_)))); \
        a_ = fmaf(w1.x,hv1.x,fmaf(w1.y,hv1.y,fmaf(w1.z,hv1.z,fmaf(w1.w,hv1.w,a_)))); \
        a_ = fmaf(w2.x,hv2.x,fmaf(w2.y,hv2.y,fmaf(w2.z,hv2.z,fmaf(w2.w,hv2.w,a_)))); \
        a_ = fmaf(w3.x,hv3.x,fmaf(w3.y,hv3.y,fmaf(w3.z,hv3.z,fmaf(w3.w,hv3.w,a_)))); \
        OUTV = a_; }
    DOTROW(0,v0) DOTROW(1,v1) DOTROW(2,v2) DOTROW(3,v3)
    DOTROW(4,v4) DOTROW(5,v5) DOTROW(6,v6) DOTROW(7,v7)
    #undef DOTROW

    const bool sA = (lane & 32) != 0;
    float a0 = (sA? v4 : v0) + __shfl_xor(sA? v0 : v4, 32, 64);
    float a1 = (sA? v5 : v1) + __shfl_xor(sA? v1 : v5, 32, 64);
    float a2 = (sA? v6 : v2) + __shfl_xor(sA? v2 : v6, 32, 64);
    float a3 = (sA? v7 : v3) + __shfl_xor(sA? v3 : v7, 32, 64);
    const bool sB = (lane & 16) != 0;
    float b0 = (sB? a2 : a0) + __shfl_xor(sB? a0 : a2, 16, 64);
    float b1 = (sB? a3 : a1) + __shfl_xor(sB? a1 : a3, 16, 64);
    const bool sC = (lane & 8) != 0;
    float c0 = (sC? b1 : b0) + __shfl_xor(sC? b0 : b1, 8, 64);
    c0 += __shfl_xor(c0, 4, 64);
    c0 += __shfl_xor(c0, 2, 64);
    c0 += __shfl_xor(c0, 1, 64);

    if (active){
      const float v  = pre_v + c0;
      const float e  = __expf(2.0f * v);
      const float hn = 1.0f - 2.0f / (e + 1.0f);
      const size_t d = dbase + myrow;
      if (t != T_STEPS - 1){
        const unsigned long long pkt =
            ((unsigned long long)(unsigned)(t + 1) << 32) |
            (unsigned long long)__float_as_uint(hn);
        __hip_atomic_store(
            reinterpret_cast<unsigned long long*>(
                tagbuf + (size_t)((t + 1) & 1)*BD + (size_t)b*DIM + d),
            pkt, __ATOMIC_RELAXED, __HIP_MEMORY_SCOPE_AGENT);
      }
      out_h[(size_t)(t+1)*BD + (size_t)b*DIM + d] = hn;
      out  [(size_t)t*BD     + (size_t)b*DIM + d] = hn * gate_v;
    }
  }
}

// ---------------------------------------------------------------------------
extern "C" void kernel_launch(void* const* d_in, const int* in_sizes, int n_in,
                              void* d_out, int out_size, void* d_ws, size_t ws_size,
                              hipStream_t stream){
  (void)in_sizes; (void)n_in; (void)out_size;
  const float* x    = (const float*)d_in[0];
  const float* z    = (const float*)d_in[1];
  const float* h0   = (const float*)d_in[2];
  const float* Wx   = (const float*)d_in[3];
  const float* Wh   = (const float*)d_in[4];
  const float* bias = (const float*)d_in[5];
  float* out   = (float*)d_out;
  float* out_h = out + OUT_SEC;

  if (ws_size >= FUSED_BYTES){
    hipMemsetAsync(d_ws, 0, FUSED_BYTES, stream);
    fused_kernel<<<NB_ALL, 512, 0, stream>>>(x, z, h0, Wx, Wh, bias, out,
                                             (unsigned*)d_ws);
  } else {
    hipMemsetAsync(d_ws, 0, TAG_BYTES, stream);
    prep_kernel<<<4096, 256, 0, stream>>>(x, Wx, bias, out_h, z, out);
    rnn_tag    <<<256, 512, 0, stream>>>(h0, Wh, out, (uint2*)d_ws);
  }
}

// Round 13
// 1108.094 us; speedup vs baseline: 5.2463x; 5.2463x over previous
//
#include <hip/hip_runtime.h>
#include <math.h>

#define T_STEPS 512
#define BATCH   16
#define DIM     1024
#define M_TOTAL (T_STEPS*BATCH)              // 8192
#define OUT_SEC ((size_t)M_TOTAL*DIM)        // 8388608 floats (output section)
#define BD      (BATCH*DIM)

// ws: tagged ping-pong exchange, 2 slots x 16 batches x 1024 packets (8B)
#define TAG_BYTES ((size_t)2*BD*8)           // 256 KB

// prep grid: 512 GEMM blocks (128x128 tile) + 2048 gate blocks
#define NB_GEMM 512
#define NB_GATE 2048

// ---------------------------------------------------------------------------
__device__ __forceinline__ float wred64(float v){
  #pragma unroll
  for (int off = 32; off >= 1; off >>= 1) v += __shfl_xor(v, off, 64);
  return v;
}

#define KA(v) asm volatile("" : "+v"(v.x), "+v"(v.y), "+v"(v.z), "+v"(v.w))

// ---------------------------------------------------------------------------
// Prep: blocks [0,512)   = pre GEMM, 128x128 tile (halved staging traffic vs
//                          64x64: 0.5 GB total fetch; ~2 blocks/CU).
//       blocks [512,2560) = entmax-1.5 gate -> output section.
__global__ __launch_bounds__(256) void prep_kernel(const float* __restrict__ X,
                                                   const float* __restrict__ Wx,
                                                   const float* __restrict__ bias,
                                                   float* __restrict__ out_h,
                                                   const float* __restrict__ z,
                                                   float* __restrict__ gate_out){
  __shared__ float As[8][128];   // k-major A tile (4 KB)
  __shared__ float Bs[8][128];   // k-major B tile (4 KB)
  const int tid = threadIdx.x;

  if (blockIdx.x < NB_GEMM){
    // ---------------- pre GEMM: 128x128 tile, 8x8 per thread ----------------
    const int bm = blockIdx.x >> 3;          // 0..63  (128 rows each)
    const int bn = blockIdx.x & 7;           // 0..7   (128 cols each)
    const int m0 = bm*128, n0 = bn*128;
    const int tx = tid & 15, ty = tid >> 4;  // 16x16 thread grid
    const int sm = tid >> 1;                 // staging row 0..127
    const int sk = (tid & 1) * 4;            // staging k offset {0,4}

    float acc[8][8] = {};

    for (int k0 = 0; k0 < DIM; k0 += 8){
      const float4 av = *reinterpret_cast<const float4*>(
          X  + (size_t)(m0+sm)*DIM + k0 + sk);
      const float4 wv = *reinterpret_cast<const float4*>(
          Wx + (size_t)(n0+sm)*DIM + k0 + sk);
      __syncthreads();
      As[sk+0][sm]=av.x; As[sk+1][sm]=av.y; As[sk+2][sm]=av.z; As[sk+3][sm]=av.w;
      Bs[sk+0][sm]=wv.x; Bs[sk+1][sm]=wv.y; Bs[sk+2][sm]=wv.z; Bs[sk+3][sm]=wv.w;
      __syncthreads();
      #pragma unroll
      for (int k = 0; k < 8; ++k){
        float af[8], bf[8];
        #pragma unroll
        for (int i = 0; i < 8; ++i) af[i] = As[k][ty + 16*i];   // broadcast reads
        #pragma unroll
        for (int j = 0; j < 8; ++j) bf[j] = Bs[k][tx + 16*j];   // conflict-free
        #pragma unroll
        for (int i = 0; i < 8; ++i)
          #pragma unroll
          for (int j = 0; j < 8; ++j) acc[i][j] = fmaf(af[i], bf[j], acc[i][j]);
      }
    }

    float bv[8];
    #pragma unroll
    for (int j = 0; j < 8; ++j) bv[j] = bias[n0 + tx + 16*j];
    #pragma unroll
    for (int i = 0; i < 8; ++i){
      // pre row m -> h slot m+BATCH (pre[t] lives where h[t+1] goes)
      float* dst = out_h + (size_t)(m0 + ty + 16*i + BATCH)*DIM + n0 + tx;
      #pragma unroll
      for (int j = 0; j < 8; ++j) dst[16*j] = acc[i][j] + bv[j];  // coalesced in tx
    }
  } else {
    // ---------------- entmax-1.5 gate (1 wave per row) ----------------
    const int gb   = blockIdx.x - NB_GEMM;
    const int row  = gb * 4 + (tid >> 6);
    const int lane = tid & 63;
    const float* zr = z + (size_t)row * DIM;

    float x[16];
    #pragma unroll
    for (int e = 0; e < 4; ++e){
      float4 v = *reinterpret_cast<const float4*>(zr + e*256 + lane*4);
      x[e*4+0]=v.x; x[e*4+1]=v.y; x[e*4+2]=v.z; x[e*4+3]=v.w;
    }

    float m = x[0];
    #pragma unroll
    for (int i = 1; i < 16; ++i) m = fmaxf(m, x[i]);
    #pragma unroll
    for (int off = 32; off >= 1; off >>= 1) m = fmaxf(m, __shfl_xor(m, off, 64));

    // binary search for tau in [m-1, m]; f(tau)=sum relu(x-tau)
    float lo = m - 1.0f, hi = m;
    for (int it = 0; it < 30; ++it){
      float mid = 0.5f*(lo + hi);
      float f = 0.f;
      #pragma unroll
      for (int i = 0; i < 16; ++i) f += fmaxf(x[i] - mid, 0.f);
      f = wred64(f);
      if (f >= 1.0f) lo = mid; else hi = mid;
    }
    float s = 0.f, kc = 0.f;
    #pragma unroll
    for (int i = 0; i < 16; ++i){ if (x[i] > lo){ s += x[i]; kc += 1.f; } }
    s = wred64(s); kc = wred64(kc);
    const float tau = (s - 1.0f) / kc;

    float p[16]; float ps = 0.f;
    #pragma unroll
    for (int i = 0; i < 16; ++i){ p[i] = sqrtf(fmaxf(x[i] - tau, 0.f)); ps += p[i]; }
    ps = wred64(ps);
    const float inv = 1.0f / (ps + 1e-10f);

    float* go = gate_out + (size_t)row * DIM;
    #pragma unroll
    for (int e = 0; e < 4; ++e){
      float4 v; v.x=p[e*4]*inv; v.y=p[e*4+1]*inv; v.z=p[e*4+2]*inv; v.w=p[e*4+3]*inv;
      *reinterpret_cast<float4*>(go + e*256 + lane*4) = v;
    }
  }
}

// ---------------------------------------------------------------------------
// Kernel C (r10, verified 897 us): persistent recurrence, self-flagging
// tagged packets + distributed poll (1 dwordx4/thread/iter) + LDS broadcast.
// Safety: a tag-(t+1) packet implies its writer completed step t (poll of
// slot t, LDS read, compute) — so overwriting slot (t+1)&1 (= slot of h[t-1])
// is safe; monotone tags, memset per launch, 8B stores atomic (r5/r9/r10).
__global__ __launch_bounds__(512, 1) void rnn_tag(const float* __restrict__ h0,
                                                  const float* __restrict__ Wh,
                                                  float* __restrict__ out,
                                                  uint2* __restrict__ tagbuf){
  float* out_h = out + OUT_SEC;
  const int tid  = threadIdx.x;
  const int lane = tid & 63;
  const int w    = tid >> 6;            // wave 0..7
  const int b    = blockIdx.x >> 4;     // batch
  const int s    = blockIdx.x & 15;     // slice
  const int dbase = s*64 + w*8;

  __shared__ float hbuf[2][DIM];        // 8 KB ping-pong broadcast buffer

  // W_h slice 8 rows x 16 cols (L1-served if not register-resident)
  float4 wreg[8][4];
  #pragma unroll
  for (int r = 0; r < 8; ++r)
    #pragma unroll
    for (int j = 0; j < 4; ++j)
      wreg[r][j] = *reinterpret_cast<const float4*>(
          Wh + (size_t)(dbase + r)*DIM + lane*4 + j*256);

  KA(wreg[0][0]); KA(wreg[0][1]); KA(wreg[0][2]); KA(wreg[0][3]);
  KA(wreg[1][0]); KA(wreg[1][1]); KA(wreg[1][2]); KA(wreg[1][3]);
  KA(wreg[2][0]); KA(wreg[2][1]); KA(wreg[2][2]); KA(wreg[2][3]);
  KA(wreg[3][0]); KA(wreg[3][1]); KA(wreg[3][2]); KA(wreg[3][3]);
  KA(wreg[4][0]); KA(wreg[4][1]); KA(wreg[4][2]); KA(wreg[4][3]);
  KA(wreg[5][0]); KA(wreg[5][1]); KA(wreg[5][2]); KA(wreg[5][3]);
  KA(wreg[6][0]); KA(wreg[6][1]); KA(wreg[6][2]); KA(wreg[6][3]);
  KA(wreg[7][0]); KA(wreg[7][1]); KA(wreg[7][2]); KA(wreg[7][3]);

  // h[0] = h0 in the validated h section (output slot 0)
  if (tid < 16)
    reinterpret_cast<float4*>(out_h + (size_t)b*DIM + s*64)[tid] =
        reinterpret_cast<const float4*>(h0 + (size_t)b*DIM + s*64)[tid];

  const int myrow   = lane >> 3;            // 0..7
  const bool active = ((lane & 7) == 0);    // 8 store lanes per wave

  for (int t = 0; t < T_STEPS; ++t){
    // prefetch pre (h slot t+1) and gate (out slot t) for this lane's row
    float pre_v = 0.f, gate_v = 0.f;
    if (active){
      const size_t d = dbase + myrow;
      pre_v  = out_h[(size_t)(t+1)*BD + (size_t)b*DIM + d];
      gate_v = out  [(size_t)t*BD     + (size_t)b*DIM + d];
    }

    // ---- acquire h[t][b] into LDS (distributed poll, 16B/thread) ----
    if (t == 0){
      const float2 hl = *reinterpret_cast<const float2*>(h0 + (size_t)b*DIM + 2*tid);
      *reinterpret_cast<float2*>(&hbuf[0][2*tid]) = hl;
    } else {
      const uint2* pp = tagbuf + (size_t)(t & 1)*BD + (size_t)b*DIM + 2*tid;
      const unsigned want = (unsigned)t;
      float4 q;
      do {
        asm volatile("global_load_dwordx4 %0, %1, off sc0 sc1\n\t"
                     "s_waitcnt vmcnt(0)"
                     : "=&v"(q) : "v"(pp) : "memory");
      } while (__float_as_uint(q.y) != want || __float_as_uint(q.w) != want);
      *reinterpret_cast<float2*>(&hbuf[t & 1][2*tid]) = make_float2(q.x, q.z);
    }
    __syncthreads();

    const float* src = &hbuf[t & 1][0];
    const float4 hv0 = *reinterpret_cast<const float4*>(src + lane*4);
    const float4 hv1 = *reinterpret_cast<const float4*>(src + 256 + lane*4);
    const float4 hv2 = *reinterpret_cast<const float4*>(src + 512 + lane*4);
    const float4 hv3 = *reinterpret_cast<const float4*>(src + 768 + lane*4);

    // ---- partials: v[r] = dot(wreg[r], hv) over this lane's 16 cols ----
    float v0,v1,v2,v3,v4,v5,v6,v7;
    {
      #define DOTROW(R, OUTV)                                            \
        { const float4 w0=wreg[R][0], w1=wreg[R][1],                     \
                       w2=wreg[R][2], w3=wreg[R][3];                     \
          float a_ = 0.f;                                                \
          a_ = fmaf(w0.x,hv0.x,fmaf(w0.y,hv0.y,fmaf(w0.z,hv0.z,fmaf(w0.w,hv0.w,a_)))); \
          a_ = fmaf(w1.x,hv1.x,fmaf(w1.y,hv1.y,fmaf(w1.z,hv1.z,fmaf(w1.w,hv1.w,a_)))); \
          a_ = fmaf(w2.x,hv2.x,fmaf(w2.y,hv2.y,fmaf(w2.z,hv2.z,fmaf(w2.w,hv2.w,a_)))); \
          a_ = fmaf(w3.x,hv3.x,fmaf(w3.y,hv3.y,fmaf(w3.z,hv3.z,fmaf(w3.w,hv3.w,a_)))); \
          OUTV = a_; }
      DOTROW(0,v0) DOTROW(1,v1) DOTROW(2,v2) DOTROW(3,v3)
      DOTROW(4,v4) DOTROW(5,v5) DOTROW(6,v6) DOTROW(7,v7)
      #undef DOTROW
    }

    // ---- 10-shuffle folded reduction; lane 8r holds row r ----
    const bool sA = (lane & 32) != 0;
    float a0 = (sA? v4 : v0) + __shfl_xor(sA? v0 : v4, 32, 64);
    float a1 = (sA? v5 : v1) + __shfl_xor(sA? v1 : v5, 32, 64);
    float a2 = (sA? v6 : v2) + __shfl_xor(sA? v2 : v6, 32, 64);
    float a3 = (sA? v7 : v3) + __shfl_xor(sA? v3 : v7, 32, 64);
    const bool sB = (lane & 16) != 0;
    float b0 = (sB? a2 : a0) + __shfl_xor(sB? a0 : a2, 16, 64);
    float b1 = (sB? a3 : a1) + __shfl_xor(sB? a1 : a3, 16, 64);
    const bool sC = (lane & 8) != 0;
    float c0 = (sC? b1 : b0) + __shfl_xor(sC? b0 : b1, 8, 64);
    c0 += __shfl_xor(c0, 4, 64);
    c0 += __shfl_xor(c0, 2, 64);
    c0 += __shfl_xor(c0, 1, 64);

    if (active){
      const float v  = pre_v + c0;
      const float e  = __expf(2.0f * v);
      const float hn = 1.0f - 2.0f / (e + 1.0f);   // tanh(v)
      const size_t d = dbase + myrow;
      if (t != T_STEPS - 1){
        // self-flagging packet (value, t+1) -> ping-pong slot; no drain
        const unsigned long long pkt =
            ((unsigned long long)(unsigned)(t + 1) << 32) |
            (unsigned long long)__float_as_uint(hn);
        __hip_atomic_store(
            reinterpret_cast<unsigned long long*>(
                tagbuf + (size_t)((t + 1) & 1)*BD + (size_t)b*DIM + d),
            pkt, __ATOMIC_RELAXED, __HIP_MEMORY_SCOPE_AGENT);
      }
      // validated h + output (cached; read only after kernel end)
      out_h[(size_t)(t+1)*BD + (size_t)b*DIM + d] = hn;
      out  [(size_t)t*BD     + (size_t)b*DIM + d] = hn * gate_v;
    }
  }
}

// ---------------------------------------------------------------------------
extern "C" void kernel_launch(void* const* d_in, const int* in_sizes, int n_in,
                              void* d_out, int out_size, void* d_ws, size_t ws_size,
                              hipStream_t stream){
  (void)in_sizes; (void)n_in; (void)out_size; (void)ws_size;
  const float* x    = (const float*)d_in[0];
  const float* z    = (const float*)d_in[1];
  const float* h0   = (const float*)d_in[2];
  const float* Wx   = (const float*)d_in[3];
  const float* Wh   = (const float*)d_in[4];
  const float* bias = (const float*)d_in[5];
  float* out   = (float*)d_out;
  float* out_h = out + OUT_SEC;

  hipMemsetAsync(d_ws, 0, TAG_BYTES, stream);
  prep_kernel<<<NB_GEMM + NB_GATE, 256, 0, stream>>>(x, Wx, bias, out_h, z, out);
  rnn_tag    <<<256, 512, 0, stream>>>(h0, Wh, out, (uint2*)d_ws);
}